// Round 13
// baseline (5344.687 us; speedup 1.0000x reference)
//
#include <hip/hip_runtime.h>
#include <hip/hip_cooperative_groups.h>
#include <math.h>

namespace cg = cooperative_groups;

#define BB 16
#define KK 4
#define VV 32000
#define DD 512
#define LL 32
#define EOS_ID 2
#define NEGINF 1.0e7f
#define ALPHA_C 0.6f
#define NROW (BB * KK)        // 64
#define NBLK 500              // col-tiles of 64 cols
#define SPLIT_S 2048.0f

typedef _Float16 f16x8 __attribute__((ext_vector_type(8)));
typedef float f32x4 __attribute__((ext_vector_type(4)));

#define GLOAD_LDS16(gp, lp) \
    __builtin_amdgcn_global_load_lds( \
        (const __attribute__((address_space(1))) void*)(gp), \
        (__attribute__((address_space(3))) void*)(lp), 16, 0, 0)

// branchless stable top-8 insert (strict >: earlier/lower index wins ties).
#define INS8(v, idx, lv, li)                                          \
    if ((v) > lv[7]) {                                                \
        bool c_[8];                                                   \
        _Pragma("unroll")                                             \
        for (int j_ = 0; j_ < 8; j_++) c_[j_] = (v) > lv[j_];         \
        _Pragma("unroll")                                             \
        for (int j_ = 7; j_ >= 1; j_--) {                             \
            lv[j_] = c_[j_] ? (c_[j_ - 1] ? lv[j_ - 1] : (v)) : lv[j_];   \
            li[j_] = c_[j_] ? (c_[j_ - 1] ? li[j_ - 1] : (idx)) : li[j_]; \
        }                                                             \
        if (c_[0]) { lv[0] = (v); li[0] = (idx); }                    \
    }

// pack h value (global row r, depth d) into MFMA A-fragment order (fp16 hi/lo split)
__device__ inline void pack_h(int r, int d, float v,
                              _Float16* __restrict__ hfrag_hi,
                              _Float16* __restrict__ hfrag_lo) {
    _Float16 hi = (_Float16)v;
    _Float16 lo = (_Float16)((v - (float)hi) * SPLIT_S);
    int rg = r >> 4;
    int ks = d >> 5;
    int lane = (r & 15) + 16 * ((d >> 3) & 3);
    int e = d & 7;
    int off = (((rg * 16 + ks) * 64) + lane) * 8 + e;
    hfrag_hi[off] = hi;
    hfrag_lo[off] = lo;
}

// ---------------- init: sequences / scores ----------------
__global__ void k_init(const int* __restrict__ initial_ids,
                       int* alive_seq, float* alive_lp,
                       int* fin_seq, float* fin_sc, int* fin_fl) {
    int tid = blockIdx.x * blockDim.x + threadIdx.x;
    int nthreads = gridDim.x * blockDim.x;
    const int SEQ = NROW * (LL + 1);
    for (int idx = tid; idx < SEQ; idx += nthreads) {
        int pos = idx % (LL + 1);
        int b = (idx / (LL + 1)) / KK;
        alive_seq[idx] = (pos == 0) ? initial_ids[b] : 0;
        fin_seq[idx] = 0;
    }
    for (int idx = tid; idx < NROW; idx += nthreads) {
        int k = idx % KK;
        alive_lp[idx] = (k == 0) ? 0.0f : -NEGINF;
        fin_sc[idx] = -NEGINF;
        fin_fl[idx] = 0;
    }
}

// ---------------- one-time: proj -> fp16 hi/lo B-fragments ----------------
__global__ __launch_bounds__(256) void k_bconv(const float* __restrict__ proj,
                                               _Float16* __restrict__ bfrag_hi,
                                               _Float16* __restrict__ bfrag_lo) {
    int ct = blockIdx.x;
    int t = threadIdx.x;
    int w = t >> 6, l = t & 63;
    int col = ct * 16 + (l & 15);
    int kg = l >> 4;
    for (int ks = w; ks < 16; ks += 4) {
        int k0 = ks * 32 + kg * 8;
        f16x8 hi, lo;
        #pragma unroll
        for (int j = 0; j < 8; j++) {
            float v = proj[(size_t)(k0 + j) * VV + col];
            _Float16 h = (_Float16)v;
            hi[j] = h;
            lo[j] = (_Float16)((v - (float)h) * SPLIT_S);
        }
        size_t off = (size_t)(ct * 16 + ks) * 64 + l;
        reinterpret_cast<f16x8*>(bfrag_hi)[off] = hi;
        reinterpret_cast<f16x8*>(bfrag_lo)[off] = lo;
    }
}

// ---------------- initial h ----------------
__global__ void k_hinit(const int* __restrict__ initial_ids,
                        const float* __restrict__ init_h,
                        const float* __restrict__ embed,
                        float* __restrict__ h_buf,
                        _Float16* __restrict__ hfrag_hi,
                        _Float16* __restrict__ hfrag_lo) {
    int row = blockIdx.x;
    int b = row >> 2;
    int t = threadIdx.x;
    int tok = initial_ids[b];
    for (int d = t; d < DD; d += 256) {
        float v = tanhf(init_h[b * DD + d] + embed[(size_t)tok * DD + d]);
        h_buf[row * DD + d] = v;
        pack_h(row, d, v, hfrag_hi, hfrag_lo);
    }
}

// ---------------- persistent cooperative kernel: all 32 steps ----------------
// 32 KB static LDS -> >=2 blocks/CU even under conservative 64KB/CU accounting.
// Phase A: grid-stride over 500 col-tiles (works at ANY grid >= 16); proven
// GEMM body, NSLOT=4 (prologue 3 slots / 6 loads; ITER waits vmcnt 4/4.../2/0;
// per-tile vmcnt(0) clean drains epilogue stores). Phase B: blocks 0..15 merge
// (order-independent stable comparator) + verbatim update tail.
__global__ __launch_bounds__(256, 2) void k_loop(
        const _Float16* __restrict__ bfrag_hi,
        const _Float16* __restrict__ bfrag_lo,
        _Float16* __restrict__ hfrag_hi,
        _Float16* __restrict__ hfrag_lo,
        const float* __restrict__ embed,
        float* h_buf, int* alive_seq, float* alive_lp,
        int* fin_seq, float* fin_sc, int* fin_fl,
        float* ptv, int* pti, float* pm, float* ps) {
    cg::grid_group grid = cg::this_grid();
    int t = threadIdx.x;
    int w = t >> 6, l = t & 63;
    int colr = l & 15;
    int kg = l >> 4;
    int lq = l * 8;

    __shared__ _Float16 Bs[4][4][2][512];   // 32 KB pool, aliased per phase

    for (int step = 0; step < LL; step++) {
        // ============== phase A: GEMM + per-tile row-reduce (grid-stride) ==============
        {
            f16x8 ah[16], al[16];
            #pragma unroll
            for (int ks = 0; ks < 16; ks++) {
                ah[ks] = *reinterpret_cast<const f16x8*>(hfrag_hi + ((w * 16 + ks) * 64 + l) * 8);
                al[ks] = *reinterpret_cast<const f16x8*>(hfrag_lo + ((w * 16 + ks) * 64 + l) * 8);
            }

            for (int tile = blockIdx.x; tile < NBLK; tile += gridDim.x) {
                int ct0 = tile * 4;
                int c0 = ct0 * 16;
                asm volatile("s_waitcnt vmcnt(0)" ::: "memory");  // drain prior loads/stores
                __builtin_amdgcn_sched_barrier(0);

                f32x4 acc1[4], acc2[4];
                #pragma unroll
                for (int c2 = 0; c2 < 4; c2++) {
                    acc1[c2] = (f32x4){0.f, 0.f, 0.f, 0.f};
                    acc2[c2] = (f32x4){0.f, 0.f, 0.f, 0.f};
                }

                auto stage = [&](int s) {
                    int slot = s & 3;
                    const _Float16* gh = bfrag_hi + (((size_t)(ct0 + w) * 16 + s) * 64 + l) * 8;
                    const _Float16* gl = bfrag_lo + (((size_t)(ct0 + w) * 16 + s) * 64 + l) * 8;
                    GLOAD_LDS16(gh, &Bs[slot][w][0][0]);
                    GLOAD_LDS16(gl, &Bs[slot][w][1][0]);
                };

                stage(0); stage(1); stage(2);   // 3 slots / 6 loads in flight

#define ITER(ks, NWAIT)                                                         \
    {                                                                           \
        asm volatile("s_waitcnt vmcnt(" #NWAIT ")" ::: "memory");               \
        __builtin_amdgcn_s_barrier();                                           \
        if ((ks) + 3 < 16) stage((ks) + 3);                                     \
        f16x8 bq[4][2];                                                         \
        _Pragma("unroll")                                                       \
        for (int c2 = 0; c2 < 4; c2++) {                                        \
            bq[c2][0] = *reinterpret_cast<const f16x8*>(&Bs[(ks) & 3][c2][0][lq]); \
            bq[c2][1] = *reinterpret_cast<const f16x8*>(&Bs[(ks) & 3][c2][1][lq]); \
        }                                                                       \
        asm volatile("s_waitcnt lgkmcnt(0)" ::: "memory");                      \
        _Pragma("unroll")                                                       \
        for (int c2 = 0; c2 < 4; c2++) {                                        \
            acc1[c2] = __builtin_amdgcn_mfma_f32_16x16x32_f16(ah[(ks)], bq[c2][0], acc1[c2], 0, 0, 0); \
            acc2[c2] = __builtin_amdgcn_mfma_f32_16x16x32_f16(ah[(ks)], bq[c2][1], acc2[c2], 0, 0, 0); \
            acc2[c2] = __builtin_amdgcn_mfma_f32_16x16x32_f16(al[(ks)], bq[c2][0], acc2[c2], 0, 0, 0); \
        }                                                                       \
    }

                ITER(0, 4)  ITER(1, 4)  ITER(2, 4)  ITER(3, 4)
                ITER(4, 4)  ITER(5, 4)  ITER(6, 4)  ITER(7, 4)
                ITER(8, 4)  ITER(9, 4)  ITER(10, 4) ITER(11, 4)
                ITER(12, 4) ITER(13, 4) ITER(14, 2) ITER(15, 0)
#undef ITER

                // ---- fused row-reduce epilogue; pool overlapped, fits 32 KB ----
                char* pool = (char*)&Bs[0][0][0][0];
                float* Cs = (float*)pool;                // [64][65] = 16640 B
                // Cs write is safe post-ITER(15)-barrier: only slot 3 (24576..) read after it
                #pragma unroll
                for (int c2 = 0; c2 < 4; c2++)
                    #pragma unroll
                    for (int j = 0; j < 4; j++)
                        Cs[(w * 16 + kg * 4 + j) * 65 + c2 * 16 + colr] =
                            acc1[c2][j] + acc2[c2][j] * (1.0f / SPLIT_S);
                __syncthreads();

                int row = t >> 2, cg2 = t & 3;
                float lv[8]; int li[8];
                #pragma unroll
                for (int j = 0; j < 8; j++) { lv[j] = -INFINITY; li[j] = 0x7fffffff; }
                float m = -INFINITY, s = 0.0f;
                #pragma unroll
                for (int cc = 0; cc < 16; cc++) {
                    float v = Cs[row * 65 + cg2 * 16 + cc];
                    int idx = c0 + cg2 * 16 + cc;
                    float M = fmaxf(m, v);
                    s = s * expf(m - M) + expf(v - M);
                    m = M;
                    INS8(v, idx, lv, li)
                }
                __syncthreads();   // Cs dead; reuse its space for lists
                float* sv  = (float*)pool;               // [256][8] = 8192
                int*   si  = (int*)  (pool + 8192);      // 8192
                float* smx = (float*)(pool + 16384);     // 1024
                float* ssm = (float*)(pool + 17408);     // 1024 (ends 18432 <= 32768)
                #pragma unroll
                for (int j = 0; j < 8; j++) { sv[t * 8 + j] = lv[j]; si[t * 8 + j] = li[j]; }
                smx[t] = m; ssm[t] = s;
                __syncthreads();
                for (int st = 2; st > 0; st >>= 1) {
                    if ((t & 3) < st) {
                        float rv[8]; int ri[8];
                        int pa = 0, pb = 0;
                        #pragma unroll
                        for (int j = 0; j < 8; j++) {
                            bool aok = pa < 8, bok = pb < 8;
                            float va = sv[t * 8 + (aok ? pa : 7)], vb = sv[(t + st) * 8 + (bok ? pb : 7)];
                            int   ia = si[t * 8 + (aok ? pa : 7)], ib = si[(t + st) * 8 + (bok ? pb : 7)];
                            bool takeA = !bok || (aok && ((va > vb) || (va == vb && ia <= ib)));
                            if (takeA) { rv[j] = va; ri[j] = ia; pa++; }
                            else       { rv[j] = vb; ri[j] = ib; pb++; }
                        }
                        #pragma unroll
                        for (int j = 0; j < 8; j++) { sv[t * 8 + j] = rv[j]; si[t * 8 + j] = ri[j]; }
                        float ma = smx[t], mb = smx[t + st];
                        float M = fmaxf(ma, mb);
                        ssm[t] = ssm[t] * expf(ma - M) + ssm[t + st] * expf(mb - M);
                        smx[t] = M;
                    }
                    __syncthreads();
                }
                if ((t & 3) == 0) {
                    size_t base = ((size_t)row * NBLK + tile) * 8;
                    #pragma unroll
                    for (int j = 0; j < 8; j++) { ptv[base + j] = sv[t * 8 + j]; pti[base + j] = si[t * 8 + j]; }
                    pm[(size_t)row * NBLK + tile] = smx[t];
                    ps[(size_t)row * NBLK + tile] = ssm[t];
                }
                __syncthreads();   // lists read done before next tile's staging
            }
        }
        __threadfence();
        grid.sync();

        // ================= phase B: merge + update (blocks 0..15) =================
        if (blockIdx.x < BB) {
            int b = blockIdx.x;
            int rloc = t >> 6, lane = t & 63;
            int grow = b * KK + rloc;

            char* pool = (char*)&Bs[0][0][0][0];
            float* msv   = (float*)pool;               // [4][64][9] = 9216 B
            int*   msi   = (int*)  (pool + 9216);      // 9216 B
            float* msm   = (float*)(pool + 18432);     // [4][64]
            float* mss   = (float*)(pool + 19456);     // [4][64]
            float* h_old = (float*)(pool + 20480);     // [4][512] = 8192 B
            int* old_a   = (int*)  (pool + 28672);     // [4][33]
            int* old_f   = (int*)  (pool + 29248);     // [4][33]
            float* lse_s = (float*)(pool + 29824);     // [4]
            float* alp_s = (float*)(pool + 29840);     // [4]
            float* clp   = (float*)(pool + 29856);     // [32]
            int*   cidx  = (int*)  (pool + 29984);     // [32]
            float* c_lp  = (float*)(pool + 30112);     // [8]
            int* c_beam  = (int*)  (pool + 30144);     // [8]
            int* c_id    = (int*)  (pool + 30176);     // [8]
            int* c_fl    = (int*)  (pool + 30208);     // [8]
            float* asc_s = (float*)(pool + 30240);     // [8]
            float* comb_s= (float*)(pool + 30272);     // [12]
            int* combfl_s= (int*)  (pool + 30320);     // [12]
            int* sel_alive=(int*)  (pool + 30368);     // [4]
            int* sel_fin = (int*)  (pool + 30384);     // [4]
            float* n_alp = (float*)(pool + 30400);     // [4]
            float* n_fsc = (float*)(pool + 30416);     // [4]
            int* n_ffl   = (int*)  (pool + 30432);     // [4]  (ends 30448 <= 32768)

            for (int idx = t; idx < KK * (LL + 1); idx += 256) {
                old_a[(idx / (LL + 1)) * 33 + idx % (LL + 1)] = alive_seq[b * KK * (LL + 1) + idx];
                old_f[(idx / (LL + 1)) * 33 + idx % (LL + 1)] = fin_seq[b * KK * (LL + 1) + idx];
            }
            for (int idx = t; idx < KK * DD; idx += 256)
                h_old[idx] = h_buf[b * KK * DD + idx];

            // ---- B1: per-lane merge of partials lane, lane+64, ... ----
            float* Av = msv + (rloc * 64 + lane) * 9;
            int*   Ai = msi + (rloc * 64 + lane) * 9;
            const float* pv = ptv + (size_t)grow * NBLK * 8;
            const int*   pi = pti + (size_t)grow * NBLK * 8;
            #pragma unroll
            for (int j = 0; j < 8; j++) { Av[j] = pv[lane * 8 + j]; Ai[j] = pi[lane * 8 + j]; }
            float m = pm[(size_t)grow * NBLK + lane], s = ps[(size_t)grow * NBLK + lane];
            for (int p = lane + 64; p < NBLK; p += 64) {
                const float* bv = pv + (size_t)p * 8;
                const int*   bi = pi + (size_t)p * 8;
                float rv[8]; int ri[8];
                int pa = 0, pb = 0;
                #pragma unroll
                for (int j = 0; j < 8; j++) {
                    bool aok = pa < 8, bok = pb < 8;
                    float va = Av[aok ? pa : 7], vb = bv[bok ? pb : 7];
                    int   ia = Ai[aok ? pa : 7], ib = bi[bok ? pb : 7];
                    bool takeA = !bok || (aok && ((va > vb) || (va == vb && ia <= ib)));
                    if (takeA) { rv[j] = va; ri[j] = ia; pa++; }
                    else       { rv[j] = vb; ri[j] = ib; pb++; }
                }
                #pragma unroll
                for (int j = 0; j < 8; j++) { Av[j] = rv[j]; Ai[j] = ri[j]; }
                float mb = pm[(size_t)grow * NBLK + p], sb = ps[(size_t)grow * NBLK + p];
                float M = fmaxf(m, mb);
                s = s * expf(m - M) + sb * expf(mb - M);
                m = M;
            }
            msm[rloc * 64 + lane] = m; mss[rloc * 64 + lane] = s;
            __syncthreads();
            // ---- B2: tree 64 -> 1 per row ----
            for (int st = 32; st > 0; st >>= 1) {
                if (lane < st) {
                    float* Bv2 = msv + (rloc * 64 + lane + st) * 9;
                    int*   Bi2 = msi + (rloc * 64 + lane + st) * 9;
                    float rv[8]; int ri[8];
                    int pa = 0, pb = 0;
                    #pragma unroll
                    for (int j = 0; j < 8; j++) {
                        bool aok = pa < 8, bok = pb < 8;
                        float va = Av[aok ? pa : 7], vb = Bv2[bok ? pb : 7];
                        int   ia = Ai[aok ? pa : 7], ib = Bi2[bok ? pb : 7];
                        bool takeA = !bok || (aok && ((va > vb) || (va == vb && ia <= ib)));
                        if (takeA) { rv[j] = va; ri[j] = ia; pa++; }
                        else       { rv[j] = vb; ri[j] = ib; pb++; }
                    }
                    #pragma unroll
                    for (int j = 0; j < 8; j++) { Av[j] = rv[j]; Ai[j] = ri[j]; }
                    float ma = msm[rloc * 64 + lane], mb = msm[rloc * 64 + lane + st];
                    float M = fmaxf(ma, mb);
                    mss[rloc * 64 + lane] = mss[rloc * 64 + lane] * expf(ma - M)
                                          + mss[rloc * 64 + lane + st] * expf(mb - M);
                    msm[rloc * 64 + lane] = M;
                }
                __syncthreads();
            }
            if (t < KK) {
                lse_s[t] = msm[t * 64] + logf(mss[t * 64]);
                alp_s[t] = alive_lp[b * KK + t];
            }
            __syncthreads();

            // ---- B3: selection tail (verbatim k_update logic) ----
            if (t < 32) {
                int row = t >> 3;
                clp[t] = msv[(row * 64) * 9 + (t & 7)] - lse_s[row] + alp_s[row];
                cidx[t] = msi[(row * 64) * 9 + (t & 7)];
            }
            __syncthreads();
            if (t < 32) {
                int row = t >> 3;
                float mylp = clp[t];
                int mykey = row * VV + cidx[t];
                int cnt = 0;
                #pragma unroll
                for (int j = 0; j < 32; j++) {
                    int kj = (j >> 3) * VV + cidx[j];
                    cnt += (clp[j] > mylp) || (clp[j] == mylp && kj < mykey);
                }
                if (cnt < 8) {
                    c_lp[cnt] = mylp; c_beam[cnt] = row; c_id[cnt] = cidx[t];
                    c_fl[cnt] = (cidx[t] == EOS_ID) ? 1 : 0;
                }
            }
            __syncthreads();
            if (t < 8) asc_s[t] = c_lp[t] + (c_fl[t] ? -NEGINF : 0.0f);
            if (t >= 64 && t < 76) {
                int j2 = t - 64;
                if (j2 < 4) { comb_s[j2] = fin_sc[b * KK + j2]; combfl_s[j2] = fin_fl[b * KK + j2]; }
                else {
                    int cc = j2 - 4;
                    float ln = powf((6.0f + (float)step) / 6.0f, ALPHA_C);
                    comb_s[j2] = c_lp[cc] / ln + (c_fl[cc] ? 0.0f : -NEGINF);
                    combfl_s[j2] = c_fl[cc];
                }
            }
            __syncthreads();
            if (t < 8) {
                float a = asc_s[t];
                int cnt = 0;
                #pragma unroll
                for (int j = 0; j < 8; j++) cnt += (asc_s[j] > a) || (asc_s[j] == a && j < t);
                if (cnt < KK) { sel_alive[cnt] = t; n_alp[cnt] = a; }
            }
            if (t >= 64 && t < 76) {
                int j2 = t - 64;
                float cval = comb_s[j2];
                int cnt = 0;
                #pragma unroll
                for (int j = 0; j < 12; j++) cnt += (comb_s[j] > cval) || (comb_s[j] == cval && j < j2);
                if (cnt < KK) { sel_fin[cnt] = j2; n_fsc[cnt] = cval; n_ffl[cnt] = combfl_s[j2]; }
            }
            __syncthreads();

            for (int idx = t; idx < KK * (LL + 1); idx += 256) {
                int j = idx / (LL + 1), p = idx % (LL + 1);
                int cand = sel_alive[j], bm = c_beam[cand];
                alive_seq[b * KK * (LL + 1) + idx] = (p == step + 1) ? c_id[cand] : old_a[bm * 33 + p];
                int src = sel_fin[j];
                int fval;
                if (src < 4) fval = old_f[src * 33 + p];
                else {
                    int c2 = src - 4, bm2 = c_beam[c2];
                    fval = (p == step + 1) ? c_id[c2] : old_a[bm2 * 33 + p];
                }
                fin_seq[b * KK * (LL + 1) + idx] = fval;
            }
            for (int idx = t; idx < KK * DD; idx += 256) {
                int j = idx >> 9, d = idx & (DD - 1);
                int cand = sel_alive[j], bm = c_beam[cand], tok = c_id[cand];
                float v = tanhf(h_old[bm * DD + d] + embed[(size_t)tok * DD + d]);
                int r = b * KK + j;
                h_buf[(size_t)r * DD + d] = v;
                pack_h(r, d, v, hfrag_hi, hfrag_lo);
            }
            if (t < KK) {
                alive_lp[b * KK + t] = n_alp[t];
                fin_sc[b * KK + t] = n_fsc[t];
                fin_fl[b * KK + t] = n_ffl[t];
            }
        }
        __threadfence();
        grid.sync();
    }
}

// ================= FALLBACK PATH: proven R10 3-kernel loop =================
#define NSLOT_FB 8
__global__ __launch_bounds__(256) void k_logits_fb(
        const _Float16* __restrict__ bfrag_hi,
        const _Float16* __restrict__ bfrag_lo,
        const _Float16* __restrict__ hfrag_hi,
        const _Float16* __restrict__ hfrag_lo,
        float* __restrict__ ptv, int* __restrict__ pti,
        float* __restrict__ pm, float* __restrict__ ps) {
    int t = threadIdx.x;
    int w = t >> 6, l = t & 63;
    int ct0 = blockIdx.x * 4;
    int c0 = ct0 * 16;
    int colr = l & 15;
    int kg = l >> 4;
    int lq = l * 8;

    __shared__ _Float16 Bs[NSLOT_FB][4][2][512];   // 64 KB

    f16x8 ah[16], al[16];
    #pragma unroll
    for (int ks = 0; ks < 16; ks++) {
        ah[ks] = *reinterpret_cast<const f16x8*>(hfrag_hi + ((w * 16 + ks) * 64 + l) * 8);
        al[ks] = *reinterpret_cast<const f16x8*>(hfrag_lo + ((w * 16 + ks) * 64 + l) * 8);
    }
    asm volatile("s_waitcnt vmcnt(0)" ::: "memory");
    __builtin_amdgcn_sched_barrier(0);

    f32x4 acc1[4], acc2[4];
    #pragma unroll
    for (int c2 = 0; c2 < 4; c2++) {
        acc1[c2] = (f32x4){0.f, 0.f, 0.f, 0.f};
        acc2[c2] = (f32x4){0.f, 0.f, 0.f, 0.f};
    }

    auto stage = [&](int s) {
        int slot = s & 7;
        const _Float16* gh = bfrag_hi + (((size_t)(ct0 + w) * 16 + s) * 64 + l) * 8;
        const _Float16* gl = bfrag_lo + (((size_t)(ct0 + w) * 16 + s) * 64 + l) * 8;
        GLOAD_LDS16(gh, &Bs[slot][w][0][0]);
        GLOAD_LDS16(gl, &Bs[slot][w][1][0]);
    };

    stage(0); stage(1); stage(2); stage(3); stage(4); stage(5); stage(6);

#define ITERF(ks, NWAIT)                                                        \
    {                                                                           \
        asm volatile("s_waitcnt vmcnt(" #NWAIT ")" ::: "memory");               \
        __builtin_amdgcn_s_barrier();                                           \
        if ((ks) + 7 < 16) stage((ks) + 7);                                     \
        f16x8 bq[4][2];                                                         \
        _Pragma("unroll")                                                       \
        for (int c2 = 0; c2 < 4; c2++) {                                        \
            bq[c2][0] = *reinterpret_cast<const f16x8*>(&Bs[(ks) & 7][c2][0][lq]); \
            bq[c2][1] = *reinterpret_cast<const f16x8*>(&Bs[(ks) & 7][c2][1][lq]); \
        }                                                                       \
        asm volatile("s_waitcnt lgkmcnt(0)" ::: "memory");                      \
        _Pragma("unroll")                                                       \
        for (int c2 = 0; c2 < 4; c2++) {                                        \
            acc1[c2] = __builtin_amdgcn_mfma_f32_16x16x32_f16(ah[(ks)], bq[c2][0], acc1[c2], 0, 0, 0); \
            acc2[c2] = __builtin_amdgcn_mfma_f32_16x16x32_f16(ah[(ks)], bq[c2][1], acc2[c2], 0, 0, 0); \
            acc2[c2] = __builtin_amdgcn_mfma_f32_16x16x32_f16(al[(ks)], bq[c2][0], acc2[c2], 0, 0, 0); \
        }                                                                       \
    }

    ITERF(0, 12)  ITERF(1, 12)  ITERF(2, 12)  ITERF(3, 12)
    ITERF(4, 12)  ITERF(5, 12)  ITERF(6, 12)  ITERF(7, 12)
    ITERF(8, 12)  ITERF(9, 12)  ITERF(10, 10) ITERF(11, 8)
    ITERF(12, 6)  ITERF(13, 4)  ITERF(14, 2)  ITERF(15, 0)
#undef ITERF

    char* pool = (char*)&Bs[0][0][0][0];
    float* Cs  = (float*)pool;
    float* sv  = (float*)(pool + 16640);
    int*   si  = (int*)  (pool + 24832);
    float* smx = (float*)(pool + 33024);
    float* ssm = (float*)(pool + 34048);

    #pragma unroll
    for (int c2 = 0; c2 < 4; c2++)
        #pragma unroll
        for (int j = 0; j < 4; j++)
            Cs[(w * 16 + kg * 4 + j) * 65 + c2 * 16 + colr] =
                acc1[c2][j] + acc2[c2][j] * (1.0f / SPLIT_S);
    __syncthreads();

    int row = t >> 2, cg2 = t & 3;
    float lv[8]; int li[8];
    #pragma unroll
    for (int j = 0; j < 8; j++) { lv[j] = -INFINITY; li[j] = 0x7fffffff; }
    float m = -INFINITY, s = 0.0f;
    #pragma unroll
    for (int cc = 0; cc < 16; cc++) {
        float v = Cs[row * 65 + cg2 * 16 + cc];
        int idx = c0 + cg2 * 16 + cc;
        float M = fmaxf(m, v);
        s = s * expf(m - M) + expf(v - M);
        m = M;
        INS8(v, idx, lv, li)
    }
    #pragma unroll
    for (int j = 0; j < 8; j++) { sv[t * 8 + j] = lv[j]; si[t * 8 + j] = li[j]; }
    smx[t] = m; ssm[t] = s;
    __syncthreads();
    for (int st = 2; st > 0; st >>= 1) {
        if ((t & 3) < st) {
            float rv[8]; int ri[8];
            int pa = 0, pb = 0;
            #pragma unroll
            for (int j = 0; j < 8; j++) {
                bool aok = pa < 8, bok = pb < 8;
                float va = sv[t * 8 + (aok ? pa : 7)], vb = sv[(t + st) * 8 + (bok ? pb : 7)];
                int   ia = si[t * 8 + (aok ? pa : 7)], ib = si[(t + st) * 8 + (bok ? pb : 7)];
                bool takeA = !bok || (aok && ((va > vb) || (va == vb && ia <= ib)));
                if (takeA) { rv[j] = va; ri[j] = ia; pa++; }
                else       { rv[j] = vb; ri[j] = ib; pb++; }
            }
            #pragma unroll
            for (int j = 0; j < 8; j++) { sv[t * 8 + j] = rv[j]; si[t * 8 + j] = ri[j]; }
            float ma = smx[t], mb = smx[t + st];
            float M = fmaxf(ma, mb);
            ssm[t] = ssm[t] * expf(ma - M) + ssm[t + st] * expf(mb - M);
            smx[t] = M;
        }
        __syncthreads();
    }
    if ((t & 3) == 0) {
        size_t base = ((size_t)row * NBLK + blockIdx.x) * 8;
        #pragma unroll
        for (int j = 0; j < 8; j++) { ptv[base + j] = sv[t * 8 + j]; pti[base + j] = si[t * 8 + j]; }
        pm[(size_t)row * NBLK + blockIdx.x] = smx[t];
        ps[(size_t)row * NBLK + blockIdx.x] = ssm[t];
    }
}

__global__ __launch_bounds__(256) void k_merge(
        const float* __restrict__ ptv, const int* __restrict__ pti,
        const float* __restrict__ pm, const float* __restrict__ ps,
        float* __restrict__ rowtop_val, int* __restrict__ rowtop_idx,
        float* __restrict__ row_lse) {
    int row = blockIdx.x, t = threadIdx.x;
    __shared__ float sval[256][8]; __shared__ int sidx[256][8];
    __shared__ float sm[256], ss[256];
    const float* pv = ptv + (size_t)row * NBLK * 8;
    const int*   pi = pti + (size_t)row * NBLK * 8;

    #pragma unroll
    for (int j = 0; j < 8; j++) { sval[t][j] = pv[t * 8 + j]; sidx[t][j] = pi[t * 8 + j]; }
    float m = pm[(size_t)row * NBLK + t], s = ps[(size_t)row * NBLK + t];
    if (t + 256 < NBLK) {
        const float* bv = pv + (size_t)(t + 256) * 8;
        const int*   bi = pi + (size_t)(t + 256) * 8;
        float rv[8]; int ri[8];
        int pa = 0, pb = 0;
        #pragma unroll
        for (int j = 0; j < 8; j++) {
            bool aok = pa < 8, bok = pb < 8;
            float va = sval[t][aok ? pa : 7], vb = bv[bok ? pb : 7];
            int   ia = sidx[t][aok ? pa : 7], ib = bi[bok ? pb : 7];
            bool takeA = !bok || (aok && ((va > vb) || (va == vb && ia <= ib)));
            if (takeA) { rv[j] = va; ri[j] = ia; pa++; }
            else       { rv[j] = vb; ri[j] = ib; pb++; }
        }
        #pragma unroll
        for (int j = 0; j < 8; j++) { sval[t][j] = rv[j]; sidx[t][j] = ri[j]; }
        float mb = pm[(size_t)row * NBLK + t + 256], sb = ps[(size_t)row * NBLK + t + 256];
        float M = fmaxf(m, mb);
        s = s * expf(m - M) + sb * expf(mb - M);
        m = M;
    }
    sm[t] = m; ss[t] = s;
    __syncthreads();
    for (int st = 128; st > 0; st >>= 1) {
        if (t < st) {
            float rv[8]; int ri[8];
            int pa = 0, pb = 0;
            #pragma unroll
            for (int j = 0; j < 8; j++) {
                bool aok = pa < 8, bok = pb < 8;
                float va = sval[t][aok ? pa : 7], vb = sval[t + st][bok ? pb : 7];
                int   ia = sidx[t][aok ? pa : 7], ib = sidx[t + st][bok ? pb : 7];
                bool takeA = !bok || (aok && ((va > vb) || (va == vb && ia <= ib)));
                if (takeA) { rv[j] = va; ri[j] = ia; pa++; }
                else       { rv[j] = vb; ri[j] = ib; pb++; }
            }
            #pragma unroll
            for (int j = 0; j < 8; j++) { sval[t][j] = rv[j]; sidx[t][j] = ri[j]; }
            float ma = sm[t], mb = sm[t + st];
            float M = fmaxf(ma, mb);
            ss[t] = ss[t] * expf(ma - M) + ss[t + st] * expf(mb - M);
            sm[t] = M;
        }
        __syncthreads();
    }
    if (t == 0) {
        #pragma unroll
        for (int j = 0; j < 8; j++) {
            rowtop_val[row * 8 + j] = sval[0][j];
            rowtop_idx[row * 8 + j] = sidx[0][j];
        }
        row_lse[row] = sm[0] + logf(ss[0]);
    }
}

__global__ __launch_bounds__(256) void k_update(
        const float* __restrict__ embed,
        float* h_buf, int* alive_seq, float* alive_lp,
        int* fin_seq, float* fin_sc, int* fin_fl,
        const float* __restrict__ rowtop_val, const int* __restrict__ rowtop_idx,
        const float* __restrict__ row_lse,
        _Float16* __restrict__ hfrag_hi, _Float16* __restrict__ hfrag_lo,
        int step) {
    int b = blockIdx.x;
    int t = threadIdx.x;
    __shared__ float h_old[KK][DD];
    __shared__ int old_aseq[KK][LL + 1], old_fseq[KK][LL + 1];
    __shared__ float lse_s[KK], alp_s[KK];
    __shared__ float clp[32]; __shared__ int cidx[32];
    __shared__ float c_lp[8];  __shared__ int c_beam[8], c_id[8], c_fl[8];
    __shared__ float asc_s[8], comb_s[12]; __shared__ int combfl_s[12];
    __shared__ int sel_alive[KK], sel_fin[KK];
    __shared__ float n_alp[KK], n_fsc[KK]; __shared__ int n_ffl[KK];

    for (int idx = t; idx < KK * (LL + 1); idx += 256) {
        old_aseq[idx / (LL + 1)][idx % (LL + 1)] = alive_seq[b * KK * (LL + 1) + idx];
        old_fseq[idx / (LL + 1)][idx % (LL + 1)] = fin_seq[b * KK * (LL + 1) + idx];
    }
    for (int idx = t; idx < KK * DD; idx += 256)
        h_old[idx >> 9][idx & (DD - 1)] = h_buf[b * KK * DD + idx];
    if (t < KK) {
        int r = b * KK + t;
        lse_s[t] = row_lse[r];
        alp_s[t] = alive_lp[r];
    }
    __syncthreads();

    if (t < 32) {
        int row = t >> 3;
        int src = (b * KK + row) * 8 + (t & 7);
        clp[t] = rowtop_val[src] - lse_s[row] + alp_s[row];
        cidx[t] = rowtop_idx[src];
    }
    __syncthreads();
    if (t < 32) {
        int row = t >> 3;
        float mylp = clp[t];
        int mykey = row * VV + cidx[t];
        int cnt = 0;
        #pragma unroll
        for (int j = 0; j < 32; j++) {
            int kj = (j >> 3) * VV + cidx[j];
            cnt += (clp[j] > mylp) || (clp[j] == mylp && kj < mykey);
        }
        if (cnt < 8) {
            c_lp[cnt] = mylp; c_beam[cnt] = row; c_id[cnt] = cidx[t];
            c_fl[cnt] = (cidx[t] == EOS_ID) ? 1 : 0;
        }
    }
    __syncthreads();
    if (t < 8) asc_s[t] = c_lp[t] + (c_fl[t] ? -NEGINF : 0.0f);
    if (t >= 64 && t < 76) {
        int j2 = t - 64;
        if (j2 < 4) { comb_s[j2] = fin_sc[b * KK + j2]; combfl_s[j2] = fin_fl[b * KK + j2]; }
        else {
            int cc = j2 - 4;
            float ln = powf((6.0f + (float)step) / 6.0f, ALPHA_C);
            comb_s[j2] = c_lp[cc] / ln + (c_fl[cc] ? 0.0f : -NEGINF);
            combfl_s[j2] = c_fl[cc];
        }
    }
    __syncthreads();
    if (t < 8) {
        float a = asc_s[t];
        int cnt = 0;
        #pragma unroll
        for (int j = 0; j < 8; j++) cnt += (asc_s[j] > a) || (asc_s[j] == a && j < t);
        if (cnt < KK) { sel_alive[cnt] = t; n_alp[cnt] = a; }
    }
    if (t >= 64 && t < 76) {
        int j2 = t - 64;
        float cval = comb_s[j2];
        int cnt = 0;
        #pragma unroll
        for (int j = 0; j < 12; j++) cnt += (comb_s[j] > cval) || (comb_s[j] == cval && j < j2);
        if (cnt < KK) { sel_fin[cnt] = j2; n_fsc[cnt] = cval; n_ffl[cnt] = combfl_s[j2]; }
    }
    __syncthreads();

    for (int idx = t; idx < KK * (LL + 1); idx += 256) {
        int j = idx / (LL + 1), p = idx % (LL + 1);
        int cand = sel_alive[j], bm = c_beam[cand];
        alive_seq[b * KK * (LL + 1) + idx] = (p == step + 1) ? c_id[cand] : old_aseq[bm][p];
        int src = sel_fin[j];
        int fval;
        if (src < 4) fval = old_fseq[src][p];
        else {
            int c2 = src - 4, bm2 = c_beam[c2];
            fval = (p == step + 1) ? c_id[c2] : old_aseq[bm2][p];
        }
        fin_seq[b * KK * (LL + 1) + idx] = fval;
    }
    for (int idx = t; idx < KK * DD; idx += 256) {
        int j = idx >> 9, d = idx & (DD - 1);
        int cand = sel_alive[j], bm = c_beam[cand], tok = c_id[cand];
        float v = tanhf(h_old[bm][d] + embed[(size_t)tok * DD + d]);
        int r = b * KK + j;
        h_buf[(size_t)r * DD + d] = v;
        pack_h(r, d, v, hfrag_hi, hfrag_lo);
    }
    if (t < KK) {
        alive_lp[b * KK + t] = n_alp[t];
        fin_sc[b * KK + t] = n_fsc[t];
        fin_fl[b * KK + t] = n_ffl[t];
    }
}

// ---------------- finalize ----------------
__global__ void k_final(const int* __restrict__ alive_seq, const float* __restrict__ alive_lp,
                        const int* __restrict__ fin_seq, const float* __restrict__ fin_sc,
                        const int* __restrict__ fin_fl, float* __restrict__ out) {
    int b = blockIdx.x;
    int t = threadIdx.x;
    __shared__ int anyf;
    if (t == 0)
        anyf = fin_fl[b * KK] | fin_fl[b * KK + 1] | fin_fl[b * KK + 2] | fin_fl[b * KK + 3];
    __syncthreads();
    for (int idx = t; idx < KK * (LL + 1); idx += blockDim.x) {
        int src = anyf ? fin_seq[b * KK * (LL + 1) + idx] : alive_seq[b * KK * (LL + 1) + idx];
        out[b * KK * (LL + 1) + idx] = (float)src;
    }
    if (t < KK)
        out[BB * KK * (LL + 1) + b * KK + t] = anyf ? fin_sc[b * KK + t] : alive_lp[b * KK + t];
}

extern "C" void kernel_launch(void* const* d_in, const int* in_sizes, int n_in,
                              void* d_out, int out_size, void* d_ws, size_t ws_size,
                              hipStream_t stream) {
    const int* initial_ids = (const int*)d_in[0];
    const float* init_h = (const float*)d_in[1];
    const float* embed = (const float*)d_in[2];
    const float* proj = (const float*)d_in[3];
    float* out = (float*)d_out;

    char* ws = (char*)d_ws;
    size_t off = 0;
    auto alloc = [&](size_t bytes) -> void* {
        off = (off + 255) & ~(size_t)255;
        void* p = ws + off;
        off += bytes;
        return p;
    };
    int* alive_seq    = (int*)alloc((size_t)NROW * (LL + 1) * 4);
    int* fin_seq      = (int*)alloc((size_t)NROW * (LL + 1) * 4);
    float* alive_lp   = (float*)alloc((size_t)NROW * 4);
    float* fin_sc     = (float*)alloc((size_t)NROW * 4);
    int* fin_fl       = (int*)alloc((size_t)NROW * 4);
    float* h_buf      = (float*)alloc((size_t)NROW * DD * 4);
    float* ptv        = (float*)alloc((size_t)NROW * NBLK * 8 * 4);
    int* pti          = (int*)alloc((size_t)NROW * NBLK * 8 * 4);
    float* pm         = (float*)alloc((size_t)NROW * NBLK * 4);
    float* ps         = (float*)alloc((size_t)NROW * NBLK * 4);
    float* rowtop_val = (float*)alloc((size_t)NROW * 8 * 4);
    int* rowtop_idx   = (int*)alloc((size_t)NROW * 8 * 4);
    float* row_lse    = (float*)alloc((size_t)NROW * 4);
    _Float16* hfrag_hi = (_Float16*)alloc((size_t)NROW * DD * 2);
    _Float16* hfrag_lo = (_Float16*)alloc((size_t)NROW * DD * 2);
    _Float16* bfrag_hi = (_Float16*)alloc((size_t)VV * DD * 2);
    _Float16* bfrag_lo = (_Float16*)alloc((size_t)VV * DD * 2);

    k_init<<<16, 256, 0, stream>>>(initial_ids, alive_seq, alive_lp,
                                   fin_seq, fin_sc, fin_fl);
    k_bconv<<<2000, 256, 0, stream>>>(proj, bfrag_hi, bfrag_lo);
    k_hinit<<<NROW, 256, 0, stream>>>(initial_ids, init_h, embed, h_buf,
                                      hfrag_hi, hfrag_lo);

    // decide coop vs fallback deterministically via the runtime's own occupancy calc
    int nbPerCU = 0;
    hipError_t qrc = hipOccupancyMaxActiveBlocksPerMultiprocessor(&nbPerCU, k_loop, 256, 0);
    int nCU = 256;
    {
        int dev = 0;
        hipGetDevice(&dev);
        hipDeviceProp_t prop;
        if (hipGetDeviceProperties(&prop, dev) == hipSuccess && prop.multiProcessorCount > 0)
            nCU = prop.multiProcessorCount;
    }
    int coopGrid = nbPerCU * nCU;
    if (coopGrid > NBLK) coopGrid = NBLK;
    bool useCoop = (qrc == hipSuccess) && (coopGrid >= BB);

    if (useCoop) {
        void* args[] = {
            (void*)&bfrag_hi, (void*)&bfrag_lo, (void*)&hfrag_hi, (void*)&hfrag_lo,
            (void*)&embed, (void*)&h_buf, (void*)&alive_seq, (void*)&alive_lp,
            (void*)&fin_seq, (void*)&fin_sc, (void*)&fin_fl,
            (void*)&ptv, (void*)&pti, (void*)&pm, (void*)&ps
        };
        hipError_t rc = hipLaunchCooperativeKernel((void*)k_loop, dim3(coopGrid), dim3(256),
                                                   args, 0, stream);
        if (rc != hipSuccess) useCoop = false;
    }
    if (!useCoop) {
        for (int step = 0; step < LL; step++) {
            k_logits_fb<<<NBLK, 256, 0, stream>>>(bfrag_hi, bfrag_lo, hfrag_hi, hfrag_lo,
                                                  ptv, pti, pm, ps);
            k_merge<<<NROW, 256, 0, stream>>>(ptv, pti, pm, ps,
                                              rowtop_val, rowtop_idx, row_lse);
            k_update<<<BB, 256, 0, stream>>>(embed, h_buf, alive_seq, alive_lp,
                                             fin_seq, fin_sc, fin_fl,
                                             rowtop_val, rowtop_idx, row_lse,
                                             hfrag_hi, hfrag_lo, step);
        }
    }
    k_final<<<BB, 64, 0, stream>>>(alive_seq, alive_lp, fin_seq, fin_sc, fin_fl, out);
}

// Round 14
// 1470.339 us; speedup vs baseline: 3.6350x; 3.6350x over previous
//
#include <hip/hip_runtime.h>
#include <math.h>

#define BB 16
#define KK 4
#define VV 32000
#define DD 512
#define LL 32
#define EOS_ID 2
#define NEGINF 1.0e7f
#define ALPHA_C 0.6f
#define NROW (BB * KK)        // 64
#define NBLK 500              // k_logits blocks, 64 cols each
#define NSLOT 8
#define SPLIT_S 2048.0f

typedef _Float16 f16x8 __attribute__((ext_vector_type(8)));
typedef float f32x4 __attribute__((ext_vector_type(4)));

#define GLOAD_LDS16(gp, lp) \
    __builtin_amdgcn_global_load_lds( \
        (const __attribute__((address_space(1))) void*)(gp), \
        (__attribute__((address_space(3))) void*)(lp), 16, 0, 0)

// branchless stable top-8 insert (strict >: earlier/lower index wins ties).
// all private indices compile-time -> stays in VGPRs (rule #20).
#define INS8(v, idx, lv, li)                                          \
    if ((v) > lv[7]) {                                                \
        bool c_[8];                                                   \
        _Pragma("unroll")                                             \
        for (int j_ = 0; j_ < 8; j_++) c_[j_] = (v) > lv[j_];         \
        _Pragma("unroll")                                             \
        for (int j_ = 7; j_ >= 1; j_--) {                             \
            lv[j_] = c_[j_] ? (c_[j_ - 1] ? lv[j_ - 1] : (v)) : lv[j_];   \
            li[j_] = c_[j_] ? (c_[j_ - 1] ? li[j_ - 1] : (idx)) : li[j_]; \
        }                                                             \
        if (c_[0]) { lv[0] = (v); li[0] = (idx); }                    \
    }

// pack h value (global row r, depth d) into MFMA A-fragment order (fp16 hi/lo split)
__device__ inline void pack_h(int r, int d, float v,
                              _Float16* __restrict__ hfrag_hi,
                              _Float16* __restrict__ hfrag_lo) {
    _Float16 hi = (_Float16)v;
    _Float16 lo = (_Float16)((v - (float)hi) * SPLIT_S);
    int rg = r >> 4;
    int ks = d >> 5;
    int lane = (r & 15) + 16 * ((d >> 3) & 3);
    int e = d & 7;
    int off = (((rg * 16 + ks) * 64) + lane) * 8 + e;
    hfrag_hi[off] = hi;
    hfrag_lo[off] = lo;
}

// ---------------- init: sequences / scores ----------------
__global__ void k_init(const int* __restrict__ initial_ids,
                       int* alive_seq, float* alive_lp,
                       int* fin_seq, float* fin_sc, int* fin_fl) {
    int tid = blockIdx.x * blockDim.x + threadIdx.x;
    int nthreads = gridDim.x * blockDim.x;
    const int SEQ = NROW * (LL + 1);
    for (int idx = tid; idx < SEQ; idx += nthreads) {
        int pos = idx % (LL + 1);
        int b = (idx / (LL + 1)) / KK;
        alive_seq[idx] = (pos == 0) ? initial_ids[b] : 0;
        fin_seq[idx] = 0;
    }
    for (int idx = tid; idx < NROW; idx += nthreads) {
        int k = idx % KK;
        alive_lp[idx] = (k == 0) ? 0.0f : -NEGINF;
        fin_sc[idx] = -NEGINF;
        fin_fl[idx] = 0;
    }
}

// ---------------- one-time: proj -> fp16 hi/lo B-fragments ----------------
__global__ __launch_bounds__(256) void k_bconv(const float* __restrict__ proj,
                                               _Float16* __restrict__ bfrag_hi,
                                               _Float16* __restrict__ bfrag_lo) {
    int ct = blockIdx.x;
    int t = threadIdx.x;
    int w = t >> 6, l = t & 63;
    int col = ct * 16 + (l & 15);
    int kg = l >> 4;
    for (int ks = w; ks < 16; ks += 4) {
        int k0 = ks * 32 + kg * 8;
        f16x8 hi, lo;
        #pragma unroll
        for (int j = 0; j < 8; j++) {
            float v = proj[(size_t)(k0 + j) * VV + col];
            _Float16 h = (_Float16)v;
            hi[j] = h;
            lo[j] = (_Float16)((v - (float)h) * SPLIT_S);
        }
        size_t off = (size_t)(ct * 16 + ks) * 64 + l;
        reinterpret_cast<f16x8*>(bfrag_hi)[off] = hi;
        reinterpret_cast<f16x8*>(bfrag_lo)[off] = lo;
    }
}

// ---------------- initial h ----------------
__global__ void k_hinit(const int* __restrict__ initial_ids,
                        const float* __restrict__ init_h,
                        const float* __restrict__ embed,
                        float* __restrict__ h_buf,
                        _Float16* __restrict__ hfrag_hi,
                        _Float16* __restrict__ hfrag_lo) {
    int row = blockIdx.x;
    int b = row >> 2;
    int t = threadIdx.x;
    int tok = initial_ids[b];
    for (int d = t; d < DD; d += 256) {
        float v = tanhf(init_h[b * DD + d] + embed[(size_t)tok * DD + d]);
        h_buf[row * DD + d] = v;
        pack_h(row, d, v, hfrag_hi, hfrag_lo);
    }
}

// ---------------- logits via MFMA fp16x2 split + fused per-block row-reduce ---------
// grid 500, block 256 (4 waves). Block: all 64 rows x 64 cols (4 col-tiles).
// Wave w: row-group w x all 4 col-tiles. A in regs; B staged 8-deep in LDS.
// Single barrier per iter: at iter ks, each wave's lgkmcnt(0) in iter ks-1 ensures
// its slot-(ks-1) reads finished before this barrier, so stage(ks+7) (overwriting
// slot (ks-1)&7) is safe right after it. Per-wave vmcnt before the barrier
// publishes that wave's staged tile to the other 3 waves.
__global__ __launch_bounds__(256) void k_logits(
        const _Float16* __restrict__ bfrag_hi,
        const _Float16* __restrict__ bfrag_lo,
        const _Float16* __restrict__ hfrag_hi,
        const _Float16* __restrict__ hfrag_lo,
        float* __restrict__ ptv, int* __restrict__ pti,
        float* __restrict__ pm, float* __restrict__ ps) {
    int t = threadIdx.x;
    int w = t >> 6, l = t & 63;
    int ct0 = blockIdx.x * 4;
    int c0 = ct0 * 16;
    int colr = l & 15;
    int kg = l >> 4;
    int lq = l * 8;

    __shared__ _Float16 Bs[NSLOT][4][2][512];   // 64 KB; reused by epilogue

    // ---- A preload: this wave's row-group, 16 k-slices, hi+lo (128 VGPRs) ----
    f16x8 ah[16], al[16];
    #pragma unroll
    for (int ks = 0; ks < 16; ks++) {
        ah[ks] = *reinterpret_cast<const f16x8*>(hfrag_hi + ((w * 16 + ks) * 64 + l) * 8);
        al[ks] = *reinterpret_cast<const f16x8*>(hfrag_lo + ((w * 16 + ks) * 64 + l) * 8);
    }
    asm volatile("s_waitcnt vmcnt(0)" ::: "memory");   // clean vmcnt for counted waits
    __builtin_amdgcn_sched_barrier(0);

    f32x4 acc1[4], acc2[4];
    #pragma unroll
    for (int c2 = 0; c2 < 4; c2++) {
        acc1[c2] = (f32x4){0.f, 0.f, 0.f, 0.f};
        acc2[c2] = (f32x4){0.f, 0.f, 0.f, 0.f};
    }

    auto stage = [&](int s) {
        int slot = s & 7;
        const _Float16* gh = bfrag_hi + (((size_t)(ct0 + w) * 16 + s) * 64 + l) * 8;
        const _Float16* gl = bfrag_lo + (((size_t)(ct0 + w) * 16 + s) * 64 + l) * 8;
        GLOAD_LDS16(gh, &Bs[slot][w][0][0]);
        GLOAD_LDS16(gl, &Bs[slot][w][1][0]);
    };

    // prologue: 7 slots in flight (14 loads/wave)
    stage(0); stage(1); stage(2); stage(3); stage(4); stage(5); stage(6);

#define ITER(ks, NWAIT)                                                         \
    {                                                                           \
        asm volatile("s_waitcnt vmcnt(" #NWAIT ")" ::: "memory");               \
        __builtin_amdgcn_s_barrier();                                           \
        if ((ks) + 7 < 16) stage((ks) + 7);                                     \
        f16x8 bq[4][2];                                                         \
        _Pragma("unroll")                                                       \
        for (int c2 = 0; c2 < 4; c2++) {                                        \
            bq[c2][0] = *reinterpret_cast<const f16x8*>(&Bs[(ks) & 7][c2][0][lq]); \
            bq[c2][1] = *reinterpret_cast<const f16x8*>(&Bs[(ks) & 7][c2][1][lq]); \
        }                                                                       \
        asm volatile("s_waitcnt lgkmcnt(0)" ::: "memory");                      \
        _Pragma("unroll")                                                       \
        for (int c2 = 0; c2 < 4; c2++) {                                        \
            acc1[c2] = __builtin_amdgcn_mfma_f32_16x16x32_f16(ah[(ks)], bq[c2][0], acc1[c2], 0, 0, 0); \
            acc2[c2] = __builtin_amdgcn_mfma_f32_16x16x32_f16(ah[(ks)], bq[c2][1], acc2[c2], 0, 0, 0); \
            acc2[c2] = __builtin_amdgcn_mfma_f32_16x16x32_f16(al[(ks)], bq[c2][0], acc2[c2], 0, 0, 0); \
        }                                                                       \
    }

    ITER(0, 12)  ITER(1, 12)  ITER(2, 12)  ITER(3, 12)
    ITER(4, 12)  ITER(5, 12)  ITER(6, 12)  ITER(7, 12)
    ITER(8, 12)  ITER(9, 12)  ITER(10, 10) ITER(11, 8)
    ITER(12, 6)  ITER(13, 4)  ITER(14, 2)  ITER(15, 0)
#undef ITER

    // ---- fused row-reduce epilogue (Bs is dead; reuse as scratch pool) ----
    char* pool = (char*)&Bs[0][0][0][0];
    float* Cs  = (float*)pool;               // [64][65] = 16640 B
    float* sv  = (float*)(pool + 16640);     // [256][8]
    int*   si  = (int*)  (pool + 24832);     // [256][8]
    float* smx = (float*)(pool + 33024);     // [256]
    float* ssm = (float*)(pool + 34048);     // [256]

    // C layout: col = lane&15, row = (lane>>4)*4 + reg
    #pragma unroll
    for (int c2 = 0; c2 < 4; c2++)
        #pragma unroll
        for (int j = 0; j < 4; j++)
            Cs[(w * 16 + kg * 4 + j) * 65 + c2 * 16 + colr] =
                acc1[c2][j] + acc2[c2][j] * (1.0f / SPLIT_S);
    __syncthreads();

    int row = t >> 2, cg = t & 3;
    float lv[8]; int li[8];
    #pragma unroll
    for (int j = 0; j < 8; j++) { lv[j] = -INFINITY; li[j] = 0x7fffffff; }
    float m = -INFINITY, s = 0.0f;
    #pragma unroll
    for (int cc = 0; cc < 16; cc++) {
        float v = Cs[row * 65 + cg * 16 + cc];
        int idx = c0 + cg * 16 + cc;
        float M = fmaxf(m, v);
        s = s * expf(m - M) + expf(v - M);
        m = M;
        INS8(v, idx, lv, li)
    }
    #pragma unroll
    for (int j = 0; j < 8; j++) { sv[t * 8 + j] = lv[j]; si[t * 8 + j] = li[j]; }
    smx[t] = m; ssm[t] = s;
    __syncthreads();
    for (int st = 2; st > 0; st >>= 1) {
        if ((t & 3) < st) {
            float rv[8]; int ri[8];
            int pa = 0, pb = 0;
            #pragma unroll
            for (int j = 0; j < 8; j++) {
                bool aok = pa < 8, bok = pb < 8;
                float va = sv[t * 8 + (aok ? pa : 7)], vb = sv[(t + st) * 8 + (bok ? pb : 7)];
                int   ia = si[t * 8 + (aok ? pa : 7)], ib = si[(t + st) * 8 + (bok ? pb : 7)];
                bool takeA = !bok || (aok && ((va > vb) || (va == vb && ia <= ib)));
                if (takeA) { rv[j] = va; ri[j] = ia; pa++; }
                else       { rv[j] = vb; ri[j] = ib; pb++; }
            }
            #pragma unroll
            for (int j = 0; j < 8; j++) { sv[t * 8 + j] = rv[j]; si[t * 8 + j] = ri[j]; }
            float ma = smx[t], mb = smx[t + st];
            float M = fmaxf(ma, mb);
            ssm[t] = ssm[t] * expf(ma - M) + ssm[t + st] * expf(mb - M);
            smx[t] = M;
        }
        __syncthreads();
    }
    if ((t & 3) == 0) {
        size_t base = ((size_t)row * NBLK + blockIdx.x) * 8;
        #pragma unroll
        for (int j = 0; j < 8; j++) { ptv[base + j] = sv[t * 8 + j]; pti[base + j] = si[t * 8 + j]; }
        pm[(size_t)row * NBLK + blockIdx.x] = smx[t];
        ps[(size_t)row * NBLK + blockIdx.x] = ssm[t];
    }
}

// ---------------- merge 500 block-partials per row -> top-8 + lse ----------------
// grid NROW, block 256
__global__ __launch_bounds__(256) void k_merge(
        const float* __restrict__ ptv, const int* __restrict__ pti,
        const float* __restrict__ pm, const float* __restrict__ ps,
        float* __restrict__ rowtop_val, int* __restrict__ rowtop_idx,
        float* __restrict__ row_lse) {
    int row = blockIdx.x, t = threadIdx.x;
    __shared__ float sval[256][8]; __shared__ int sidx[256][8];
    __shared__ float sm[256], ss[256];
    const float* pv = ptv + (size_t)row * NBLK * 8;
    const int*   pi = pti + (size_t)row * NBLK * 8;

    #pragma unroll
    for (int j = 0; j < 8; j++) { sval[t][j] = pv[t * 8 + j]; sidx[t][j] = pi[t * 8 + j]; }
    float m = pm[(size_t)row * NBLK + t], s = ps[(size_t)row * NBLK + t];
    if (t + 256 < NBLK) {
        const float* bv = pv + (size_t)(t + 256) * 8;
        const int*   bi = pi + (size_t)(t + 256) * 8;
        float rv[8]; int ri[8];
        int pa = 0, pb = 0;
        #pragma unroll
        for (int j = 0; j < 8; j++) {
            bool aok = pa < 8, bok = pb < 8;
            float va = sval[t][aok ? pa : 7], vb = bv[bok ? pb : 7];
            int   ia = sidx[t][aok ? pa : 7], ib = bi[bok ? pb : 7];
            bool takeA = !bok || (aok && ((va > vb) || (va == vb && ia <= ib)));
            if (takeA) { rv[j] = va; ri[j] = ia; pa++; }
            else       { rv[j] = vb; ri[j] = ib; pb++; }
        }
        #pragma unroll
        for (int j = 0; j < 8; j++) { sval[t][j] = rv[j]; sidx[t][j] = ri[j]; }
        float mb = pm[(size_t)row * NBLK + t + 256], sb = ps[(size_t)row * NBLK + t + 256];
        float M = fmaxf(m, mb);
        s = s * expf(m - M) + sb * expf(mb - M);
        m = M;
    }
    sm[t] = m; ss[t] = s;
    __syncthreads();
    for (int st = 128; st > 0; st >>= 1) {
        if (t < st) {
            float rv[8]; int ri[8];
            int pa = 0, pb = 0;
            #pragma unroll
            for (int j = 0; j < 8; j++) {
                bool aok = pa < 8, bok = pb < 8;
                float va = sval[t][aok ? pa : 7], vb = sval[t + st][bok ? pb : 7];
                int   ia = sidx[t][aok ? pa : 7], ib = sidx[t + st][bok ? pb : 7];
                bool takeA = !bok || (aok && ((va > vb) || (va == vb && ia <= ib)));
                if (takeA) { rv[j] = va; ri[j] = ia; pa++; }
                else       { rv[j] = vb; ri[j] = ib; pb++; }
            }
            #pragma unroll
            for (int j = 0; j < 8; j++) { sval[t][j] = rv[j]; sidx[t][j] = ri[j]; }
            float ma = sm[t], mb = sm[t + st];
            float M = fmaxf(ma, mb);
            ss[t] = ss[t] * expf(ma - M) + ss[t + st] * expf(mb - M);
            sm[t] = M;
        }
        __syncthreads();
    }
    if (t == 0) {
        #pragma unroll
        for (int j = 0; j < 8; j++) {
            rowtop_val[row * 8 + j] = sval[0][j];
            rowtop_idx[row * 8 + j] = sidx[0][j];
        }
        row_lse[row] = sm[0] + logf(ss[0]);
    }
}

// ---------------- beam update: parallel rank-based selection ----------------
// grid BB, block 256
__global__ __launch_bounds__(256) void k_update(
        const float* __restrict__ embed,
        float* h_buf, int* alive_seq, float* alive_lp,
        int* fin_seq, float* fin_sc, int* fin_fl,
        const float* __restrict__ rowtop_val, const int* __restrict__ rowtop_idx,
        const float* __restrict__ row_lse,
        _Float16* __restrict__ hfrag_hi, _Float16* __restrict__ hfrag_lo,
        int step) {
    int b = blockIdx.x;
    int t = threadIdx.x;
    __shared__ float h_old[KK][DD];
    __shared__ int old_aseq[KK][LL + 1], old_fseq[KK][LL + 1];
    __shared__ float lse_s[KK], alp_s[KK];
    __shared__ float clp[32]; __shared__ int cidx[32];
    __shared__ float c_lp[8];  __shared__ int c_beam[8], c_id[8], c_fl[8];
    __shared__ float asc_s[8], comb_s[12]; __shared__ int combfl_s[12];
    __shared__ int sel_alive[KK], sel_fin[KK];
    __shared__ float n_alp[KK], n_fsc[KK]; __shared__ int n_ffl[KK];

    for (int idx = t; idx < KK * (LL + 1); idx += 256) {
        old_aseq[idx / (LL + 1)][idx % (LL + 1)] = alive_seq[b * KK * (LL + 1) + idx];
        old_fseq[idx / (LL + 1)][idx % (LL + 1)] = fin_seq[b * KK * (LL + 1) + idx];
    }
    for (int idx = t; idx < KK * DD; idx += 256)
        h_old[idx >> 9][idx & (DD - 1)] = h_buf[b * KK * DD + idx];
    if (t < KK) {
        int r = b * KK + t;
        lse_s[t] = row_lse[r];
        alp_s[t] = alive_lp[r];
    }
    __syncthreads();

    // 32 candidates = 4 rows x 8. lp = logit - lse + alive_lp.
    if (t < 32) {
        int row = t >> 3;
        int src = (b * KK + row) * 8 + (t & 7);
        clp[t] = rowtop_val[src] - lse_s[row] + alp_s[row];
        cidx[t] = rowtop_idx[src];
    }
    __syncthreads();
    if (t < 32) {   // stable rank (tie key = row*V + token) -> top-8
        int row = t >> 3;
        float mylp = clp[t];
        int mykey = row * VV + cidx[t];
        int cnt = 0;
        #pragma unroll
        for (int j = 0; j < 32; j++) {
            int kj = (j >> 3) * VV + cidx[j];
            cnt += (clp[j] > mylp) || (clp[j] == mylp && kj < mykey);
        }
        if (cnt < 8) {
            c_lp[cnt] = mylp; c_beam[cnt] = row; c_id[cnt] = cidx[t];
            c_fl[cnt] = (cidx[t] == EOS_ID) ? 1 : 0;
        }
    }
    __syncthreads();
    if (t < 8) asc_s[t] = c_lp[t] + (c_fl[t] ? -NEGINF : 0.0f);
    if (t >= 64 && t < 76) {
        int j2 = t - 64;
        if (j2 < 4) { comb_s[j2] = fin_sc[b * KK + j2]; combfl_s[j2] = fin_fl[b * KK + j2]; }
        else {
            int cc = j2 - 4;
            float ln = powf((6.0f + (float)step) / 6.0f, ALPHA_C);
            comb_s[j2] = c_lp[cc] / ln + (c_fl[cc] ? 0.0f : -NEGINF);
            combfl_s[j2] = c_fl[cc];
        }
    }
    __syncthreads();
    if (t < 8) {   // alive: stable top-4 (ties: lower position)
        float a = asc_s[t];
        int cnt = 0;
        #pragma unroll
        for (int j = 0; j < 8; j++) cnt += (asc_s[j] > a) || (asc_s[j] == a && j < t);
        if (cnt < KK) { sel_alive[cnt] = t; n_alp[cnt] = a; }
    }
    if (t >= 64 && t < 76) {  // finished: stable top-4 (ties: lower position)
        int j2 = t - 64;
        float cval = comb_s[j2];
        int cnt = 0;
        #pragma unroll
        for (int j = 0; j < 12; j++) cnt += (comb_s[j] > cval) || (comb_s[j] == cval && j < j2);
        if (cnt < KK) { sel_fin[cnt] = j2; n_fsc[cnt] = cval; n_ffl[cnt] = combfl_s[j2]; }
    }
    __syncthreads();

    for (int idx = t; idx < KK * (LL + 1); idx += 256) {
        int j = idx / (LL + 1), p = idx % (LL + 1);
        int cand = sel_alive[j], bm = c_beam[cand];
        alive_seq[b * KK * (LL + 1) + idx] = (p == step + 1) ? c_id[cand] : old_aseq[bm][p];
        int src = sel_fin[j];
        int fval;
        if (src < 4) fval = old_fseq[src][p];
        else {
            int c2 = src - 4, bm2 = c_beam[c2];
            fval = (p == step + 1) ? c_id[c2] : old_aseq[bm2][p];
        }
        fin_seq[b * KK * (LL + 1) + idx] = fval;
    }
    for (int idx = t; idx < KK * DD; idx += 256) {
        int j = idx >> 9, d = idx & (DD - 1);
        int cand = sel_alive[j], bm = c_beam[cand], tok = c_id[cand];
        float v = tanhf(h_old[bm][d] + embed[(size_t)tok * DD + d]);
        int r = b * KK + j;
        h_buf[(size_t)r * DD + d] = v;
        pack_h(r, d, v, hfrag_hi, hfrag_lo);
    }
    if (t < KK) {
        alive_lp[b * KK + t] = n_alp[t];
        fin_sc[b * KK + t] = n_fsc[t];
        fin_fl[b * KK + t] = n_ffl[t];
    }
}

// ---------------- finalize ----------------
__global__ void k_final(const int* __restrict__ alive_seq, const float* __restrict__ alive_lp,
                        const int* __restrict__ fin_seq, const float* __restrict__ fin_sc,
                        const int* __restrict__ fin_fl, float* __restrict__ out) {
    int b = blockIdx.x;
    int t = threadIdx.x;
    __shared__ int anyf;
    if (t == 0)
        anyf = fin_fl[b * KK] | fin_fl[b * KK + 1] | fin_fl[b * KK + 2] | fin_fl[b * KK + 3];
    __syncthreads();
    for (int idx = t; idx < KK * (LL + 1); idx += blockDim.x) {
        int src = anyf ? fin_seq[b * KK * (LL + 1) + idx] : alive_seq[b * KK * (LL + 1) + idx];
        out[b * KK * (LL + 1) + idx] = (float)src;
    }
    if (t < KK)
        out[BB * KK * (LL + 1) + b * KK + t] = anyf ? fin_sc[b * KK + t] : alive_lp[b * KK + t];
}

extern "C" void kernel_launch(void* const* d_in, const int* in_sizes, int n_in,
                              void* d_out, int out_size, void* d_ws, size_t ws_size,
                              hipStream_t stream) {
    const int* initial_ids = (const int*)d_in[0];
    const float* init_h = (const float*)d_in[1];
    const float* embed = (const float*)d_in[2];
    const float* proj = (const float*)d_in[3];
    float* out = (float*)d_out;

    char* ws = (char*)d_ws;
    size_t off = 0;
    auto alloc = [&](size_t bytes) -> void* {
        off = (off + 255) & ~(size_t)255;
        void* p = ws + off;
        off += bytes;
        return p;
    };
    int* alive_seq    = (int*)alloc((size_t)NROW * (LL + 1) * 4);
    int* fin_seq      = (int*)alloc((size_t)NROW * (LL + 1) * 4);
    float* alive_lp   = (float*)alloc((size_t)NROW * 4);
    float* fin_sc     = (float*)alloc((size_t)NROW * 4);
    int* fin_fl       = (int*)alloc((size_t)NROW * 4);
    float* h_buf      = (float*)alloc((size_t)NROW * DD * 4);
    float* ptv        = (float*)alloc((size_t)NROW * NBLK * 8 * 4);
    int* pti          = (int*)alloc((size_t)NROW * NBLK * 8 * 4);
    float* pm         = (float*)alloc((size_t)NROW * NBLK * 4);
    float* ps         = (float*)alloc((size_t)NROW * NBLK * 4);
    float* rowtop_val = (float*)alloc((size_t)NROW * 8 * 4);
    int* rowtop_idx   = (int*)alloc((size_t)NROW * 8 * 4);
    float* row_lse    = (float*)alloc((size_t)NROW * 4);
    _Float16* hfrag_hi = (_Float16*)alloc((size_t)NROW * DD * 2);
    _Float16* hfrag_lo = (_Float16*)alloc((size_t)NROW * DD * 2);
    _Float16* bfrag_hi = (_Float16*)alloc((size_t)VV * DD * 2);
    _Float16* bfrag_lo = (_Float16*)alloc((size_t)VV * DD * 2);

    k_init<<<16, 256, 0, stream>>>(initial_ids, alive_seq, alive_lp,
                                   fin_seq, fin_sc, fin_fl);
    k_bconv<<<2000, 256, 0, stream>>>(proj, bfrag_hi, bfrag_lo);
    k_hinit<<<NROW, 256, 0, stream>>>(initial_ids, init_h, embed, h_buf,
                                      hfrag_hi, hfrag_lo);
    for (int step = 0; step < LL; step++) {
        k_logits<<<NBLK, 256, 0, stream>>>(bfrag_hi, bfrag_lo, hfrag_hi, hfrag_lo,
                                           ptv, pti, pm, ps);
        k_merge<<<NROW, 256, 0, stream>>>(ptv, pti, pm, ps,
                                          rowtop_val, rowtop_idx, row_lse);
        k_update<<<BB, 256, 0, stream>>>(embed, h_buf, alive_seq, alive_lp,
                                         fin_seq, fin_sc, fin_fl,
                                         rowtop_val, rowtop_idx, row_lse,
                                         hfrag_hi, hfrag_lo, step);
    }
    k_final<<<BB, 64, 0, stream>>>(alive_seq, alive_lp, fin_seq, fin_sc, fin_fl, out);
}